// Round 10
// baseline (613.424 us; speedup 1.0000x reference)
//
#include <hip/hip_runtime.h>

// B=2, L=4096, D=512, H=8, DK=64. out = Attn(x W_qkv^T) W_o^T, fp32 io.
// R10: attn = R6's key-split inner loop (wave = 64 qrows x 32 keys; halves
// K/V frag LDS reads; P wave-private stride-40) + R8's single-buffer 2-barrier
// staging => 36.9 KB LDS = 3 blocks/CU (128 KiB pool, measured). K=32 MFMA
// only (K=16 proven regression twice). out_gemm: N-tile 64 -> 512 blocks
// (2/CU instead of 1/CU). qkv/castall/combine = R8 verbatim.

#define Bq 2
#define Lq 4096
#define Dq 512
#define Hq 8
#define DKq 64
#define PST 40  // P row stride (elems): 80B = 16B-aligned (R6-proven)

using short8  = __attribute__((ext_vector_type(8))) short;
using ushort8 = __attribute__((ext_vector_type(8))) unsigned short;
using float4v = __attribute__((ext_vector_type(4))) float;
using half4   = __attribute__((ext_vector_type(4))) _Float16;
typedef unsigned short u16;
typedef unsigned int   u32;

__device__ __forceinline__ u16 f2bf(float f) {
    u32 u = __float_as_uint(f);
    u += 0x7fffu + ((u >> 16) & 1u);   // RNE
    return (u16)(u >> 16);
}

__device__ __forceinline__ float exp2fast(float x) {
#if __has_builtin(__builtin_amdgcn_exp2f)
    return __builtin_amdgcn_exp2f(x);
#else
    return exp2f(x);
#endif
}

__device__ __forceinline__ float4v mfma16(short8 a, short8 b, float4v c) {
    return __builtin_amdgcn_mfma_f32_16x16x32_bf16(a, b, c, 0, 0, 0);
}

__device__ __forceinline__ void gload_lds16(const u16* g, u16* l) {
    __builtin_amdgcn_global_load_lds(
        (const __attribute__((address_space(1))) unsigned int*)g,
        (__attribute__((address_space(3))) unsigned int*)l,
        16, 0, 0);
}

// ---------------- fused cast fp32 -> bf16 ----------------
__global__ __launch_bounds__(256) void castall(const float* __restrict__ x,
                                               const float* __restrict__ wq,
                                               const float* __restrict__ wo,
                                               u16* __restrict__ xb,
                                               u16* __restrict__ wqb,
                                               u16* __restrict__ wob) {
    int g = blockIdx.x;
    const float* s; u16* d; int base;
    if (g < 4096)      { s = x;  d = xb;  base = g * 1024; }
    else if (g < 4864) { s = wq; d = wqb; base = (g - 4096) * 1024; }
    else               { s = wo; d = wob; base = (g - 4864) * 1024; }
    int i = base + threadIdx.x * 4;
    float4 f = *(const float4*)&s[i];
    ushort4 o;
    o.x = f2bf(f.x); o.y = f2bf(f.y); o.z = f2bf(f.z); o.w = f2bf(f.w);
    *(ushort4*)&d[i] = o;
}

// ---------------- QKV proj: 128x128 tile; LDS-bounced coalesced epilogue -----
// q prescaled by 0.125*log2(e) (softmax in exp2 domain); k,v plain.
__global__ __launch_bounds__(256) void qkv_gemm(const u16* __restrict__ A,
                                                const u16* __restrict__ Bw,
                                                u16* __restrict__ qb,
                                                u16* __restrict__ kb,
                                                u16* __restrict__ vt) {
    __shared__ __align__(16) union {
        struct { u16 A[128 * 64]; u16 B[128 * 64]; } s;
        u16 epi[128 * 134];
    } sm;
    const int m0 = blockIdx.x * 128, n0 = blockIdx.y * 128;
    const int tid = threadIdx.x, w = tid >> 6, lane = tid & 63;
    const int l15 = lane & 15, quad = lane >> 4;
    const int wy = w & 1, wx = w >> 1;
    const int r8 = lane >> 3, c8 = lane & 7, csw = c8 ^ r8;
    const int sw = l15 & 7;

    float4v acc[4][4];
    float4v zero = {0.f, 0.f, 0.f, 0.f};
#pragma unroll
    for (int mi = 0; mi < 4; mi++)
#pragma unroll
        for (int ni = 0; ni < 4; ni++) acc[mi][ni] = zero;

    for (int k0 = 0; k0 < 512; k0 += 64) {
#pragma unroll
        for (int i = 0; i < 4; i++) {
            int row = w * 32 + i * 8;
            gload_lds16(&A[(size_t)(m0 + row + r8) * 512 + k0 + csw * 8], &sm.s.A[row * 64]);
            gload_lds16(&Bw[(size_t)(n0 + row + r8) * 512 + k0 + csw * 8], &sm.s.B[row * 64]);
        }
        __syncthreads();
        short8 af0[4], af1[4], bf0[4], bf1[4];
#pragma unroll
        for (int t = 0; t < 4; t++) {
            int rowA = wy * 64 + t * 16 + l15;
            af0[t] = *(const short8*)&sm.s.A[rowA * 64 + ((quad ^ sw) * 8)];
            af1[t] = *(const short8*)&sm.s.A[rowA * 64 + (((quad + 4) ^ sw) * 8)];
            int rowB = wx * 64 + t * 16 + l15;
            bf0[t] = *(const short8*)&sm.s.B[rowB * 64 + ((quad ^ sw) * 8)];
            bf1[t] = *(const short8*)&sm.s.B[rowB * 64 + (((quad + 4) ^ sw) * 8)];
        }
#pragma unroll
        for (int mi = 0; mi < 4; mi++)
#pragma unroll
            for (int ni = 0; ni < 4; ni++) {
                acc[mi][ni] = mfma16(af0[mi], bf0[ni], acc[mi][ni]);
                acc[mi][ni] = mfma16(af1[mi], bf1[ni], acc[mi][ni]);
            }
        __syncthreads();
    }

    const int sel = n0 >> 9;   // block-uniform: 0=q,1=k,2=v
    if (sel < 2) {
        const float sc = (sel == 0) ? 0.18033688f : 1.0f;  // 0.125*log2(e)
#pragma unroll
        for (int mi = 0; mi < 4; mi++)
#pragma unroll
            for (int ni = 0; ni < 4; ni++)
#pragma unroll
                for (int r = 0; r < 4; r++)
                    sm.epi[(wy * 64 + mi * 16 + quad * 4 + r) * 134 + wx * 64 + ni * 16 + l15] =
                        f2bf(acc[mi][ni][r] * sc);
        __syncthreads();
        u16* tgt = (sel == 0) ? qb : kb;
#pragma unroll
        for (int i = 0; i < 8; i++) {
            int flat = i * 2048 + tid * 8;
            int row = flat >> 7, col = flat & 127;
            ushort8 vv = *(const ushort8*)&sm.epi[row * 134 + col];
            int dg = (n0 & 511) + col, h = dg >> 6, dk = dg & 63;
            int mm = m0 + row, b = mm >> 12, l = mm & 4095;
            *(ushort8*)&tgt[((size_t)(b * Hq + h) * Lq + l) * DKq + dk] = vv;
        }
    } else {
#pragma unroll
        for (int mi = 0; mi < 4; mi++)
#pragma unroll
            for (int ni = 0; ni < 4; ni++) {
                ushort4 v4;
                v4.x = f2bf(acc[mi][ni][0]); v4.y = f2bf(acc[mi][ni][1]);
                v4.z = f2bf(acc[mi][ni][2]); v4.w = f2bf(acc[mi][ni][3]);
                *(ushort4*)&sm.epi[(wx * 64 + ni * 16 + l15) * 134 + wy * 64 + mi * 16 + quad * 4] = v4;
            }
        __syncthreads();
#pragma unroll
        for (int i = 0; i < 8; i++) {
            int flat = i * 2048 + tid * 8;
            int vrow = flat >> 7, vcol = flat & 127;
            ushort8 vv = *(const ushort8*)&sm.epi[vrow * 134 + vcol];
            int dg = (n0 & 511) + vrow, h = dg >> 6, dk = dg & 63;
            int mm = m0 + vcol, b = mm >> 12, l = mm & 4095;
            *(ushort8*)&vt[((size_t)(b * Hq + h) * DKq + dk) * Lq + l] = vv;
        }
    }
}

// ---------------- attention: key-split waves, single-buffer K/V, P in LDS ---
__global__ __launch_bounds__(256, 4) void attn_kern(const u16* __restrict__ qb,
                                                    const u16* __restrict__ kb,
                                                    const u16* __restrict__ vt,
                                                    _Float16* __restrict__ op0,
                                                    _Float16* __restrict__ op1,
                                                    float* __restrict__ denp) {
    // Ks 4096 + Vs 4096 + Ps 4*2560 = 18432 u16 = 36,864 B -> 3 blocks/CU
    __shared__ __align__(16) u16 SM[18432];
    u16* Ks = SM;
    u16* Vs = SM + 4096;
    const int g = blockIdx.x;          // 1024
    const int xcd = g & 7, idx = g >> 3;
    const int bh = xcd * 2 + (idx & 1);
    const int rest = idx >> 1;
    const int split = rest & 1;
    const int q0 = (rest >> 1) * 128;
    const int tid = threadIdx.x;
    const int w = tid >> 6, lane = tid & 63, l15 = lane & 15, quad = lane >> 4;
    const int wq = w & 1, wk = w >> 1;              // q-half, key-half
    const int r8 = lane >> 3, c8 = lane & 7, csw = c8 ^ r8;
    const int sw = l15 & 7;
    u16* Pw = SM + 8192 + w * 64 * PST;             // wave-private P (64 x 40)

    const u16* qbase = qb + (size_t)bh * Lq * DKq;
    const u16* kbase = kb + (size_t)bh * Lq * DKq;
    const u16* vbase = vt + (size_t)bh * DKq * Lq;

    // Q fragments (B-operand of S^T), 4 rowsets of 16; q pre-scaled.
    short8 aq0[4], aq1[4];
#pragma unroll
    for (int s = 0; s < 4; s++) {
        int qrow = q0 + wq * 64 + s * 16 + l15;
        aq0[s] = *(const short8*)&qbase[(size_t)qrow * DKq + quad * 8];
        aq1[s] = *(const short8*)&qbase[(size_t)qrow * DKq + 32 + quad * 8];
    }

    short8 ones8;
#pragma unroll
    for (int j = 0; j < 8; j++) ones8[j] = (short)0x3F80;  // bf16 1.0

    float4v zero = {0.f, 0.f, 0.f, 0.f};
    float4v oacc[4][4], den[4];
#pragma unroll
    for (int s = 0; s < 4; s++) {
        den[s] = zero;
#pragma unroll
        for (int n = 0; n < 4; n++) oacc[s][n] = zero;
    }

    const int j0base = split * 2048;

    for (int jt = 0; jt < 32; jt++) {
        int j0 = j0base + jt * 64;
        if (w < 2) {
#pragma unroll
            for (int i = 0; i < 4; i++) {
                int base = w * 32 + i * 8;
                gload_lds16(&kbase[(size_t)(j0 + base + r8) * DKq + csw * 8], &Ks[base * 64]);
            }
        } else {
#pragma unroll
            for (int i = 0; i < 4; i++) {
                int base = (w - 2) * 32 + i * 8;
                gload_lds16(&vbase[(size_t)(base + r8) * Lq + j0 + csw * 8], &Vs[base * 64]);
            }
        }
        __syncthreads();

        // V frags for this wave's 32 keys (b128 each, reused across rowsets)
        short8 vf[4];
#pragma unroll
        for (int n = 0; n < 4; n++)
            vf[n] = *(const short8*)&Vs[(n * 16 + l15) * 64 + (((wk * 4 + quad) ^ sw) * 8)];

        // S^T = K Q^T over wave's 32 keys; P = exp2 -> wave-private LDS
#pragma unroll
        for (int kg = 0; kg < 2; kg++) {
            int krow = wk * 32 + kg * 16 + l15;
            short8 k0 = *(const short8*)&Ks[krow * 64 + ((quad ^ sw) * 8)];
            short8 k1 = *(const short8*)&Ks[krow * 64 + (((quad + 4) ^ sw) * 8)];
#pragma unroll
            for (int s = 0; s < 4; s++) {
                float4v sv = mfma16(k0, aq0[s], zero);
                sv = mfma16(k1, aq1[s], sv);
                u32 u0 = __float_as_uint(exp2fast(sv[0])) + 0x8000u;
                u32 u1 = __float_as_uint(exp2fast(sv[1])) + 0x8000u;
                u32 u2 = __float_as_uint(exp2fast(sv[2])) + 0x8000u;
                u32 u3 = __float_as_uint(exp2fast(sv[3])) + 0x8000u;
                uint2 pv;
                pv.x = __builtin_amdgcn_perm(u1, u0, 0x07060302u);
                pv.y = __builtin_amdgcn_perm(u3, u2, 0x07060302u);
                *(uint2*)&Pw[(s * 16 + l15) * PST + kg * 16 + quad * 4] = pv;
            }
        }

        // O += P V ; den += P . 1   (K=32 over wave's 32 keys)
#pragma unroll
        for (int s = 0; s < 4; s++) {
            short8 ap = *(const short8*)&Pw[(s * 16 + l15) * PST + quad * 8];
            den[s] = mfma16(ap, ones8, den[s]);
#pragma unroll
            for (int n = 0; n < 4; n++)
                oacc[s][n] = mfma16(ap, vf[n], oacc[s][n]);
        }
        __syncthreads();
    }

    // cross-wave combine over key-halves: wk=1 dumps, wk=0 adds (R6-proven).
    float4v* sc4 = (float4v*)SM;
    if (wk == 1) {
        float4v* dst = sc4 + (size_t)(wq * 64 + lane) * 12;
#pragma unroll
        for (int s = 0; s < 4; s++) dst[s] = den[s];
#pragma unroll
        for (int s = 0; s < 2; s++)
#pragma unroll
            for (int n = 0; n < 4; n++) dst[4 + s * 4 + n] = oacc[s][n];
    }
    __syncthreads();
    if (wk == 0) {
        float4v* src = sc4 + (size_t)(wq * 64 + lane) * 12;
#pragma unroll
        for (int s = 0; s < 4; s++) den[s] += src[s];
#pragma unroll
        for (int s = 0; s < 2; s++)
#pragma unroll
            for (int n = 0; n < 4; n++) oacc[s][n] += src[4 + s * 4 + n];
    }
    __syncthreads();
    if (wk == 1) {
        float4v* dst = sc4 + (size_t)(wq * 64 + lane) * 8;
#pragma unroll
        for (int s = 2; s < 4; s++)
#pragma unroll
            for (int n = 0; n < 4; n++) dst[(s - 2) * 4 + n] = oacc[s][n];
    }
    __syncthreads();
    if (wk == 0) {
        float4v* src = sc4 + (size_t)(wq * 64 + lane) * 8;
#pragma unroll
        for (int s = 2; s < 4; s++)
#pragma unroll
            for (int n = 0; n < 4; n++) oacc[s][n] += src[(s - 2) * 4 + n];

        _Float16* op = split ? op1 : op0;
#pragma unroll
        for (int s = 0; s < 4; s++)
#pragma unroll
            for (int r = 0; r < 4; r++) {
                float dv = den[s][r];
                float rd = __builtin_amdgcn_rcpf(dv);
                int row = q0 + wq * 64 + s * 16 + quad * 4 + r;
                if (l15 == 0) denp[(size_t)(split * 16 + bh) * Lq + row] = dv;
#pragma unroll
                for (int n = 0; n < 4; n++)
                    op[((size_t)bh * Lq + row) * DKq + n * 16 + l15] =
                        (_Float16)(oacc[s][n][r] * rd);
            }
    }
}

// ---------------- combine: ctx = (o0*d0 + o1*d1)/(d0+d1), bf16 --------------
__global__ __launch_bounds__(256) void combine(const _Float16* __restrict__ op0,
                                               const _Float16* __restrict__ op1,
                                               const float* __restrict__ denp,
                                               u16* __restrict__ ctxq) {
    int t = blockIdx.x * 256 + threadIdx.x;  // 1,048,576
    int dk4 = t & 15, l = (t >> 4) & 4095, bh = t >> 16;
    size_t r0 = (size_t)bh * Lq + l;
    half4 h0 = *(const half4*)&op0[r0 * DKq + dk4 * 4];
    half4 h1 = *(const half4*)&op1[r0 * DKq + dk4 * 4];
    float d0 = denp[r0];
    float d1 = denp[(size_t)(16 + bh) * Lq + l];
    float rs = __builtin_amdgcn_rcpf(d0 + d1);
    int b = bh >> 3, h = bh & 7;
    ushort4 o;
    o.x = f2bf(((float)h0.x * d0 + (float)h1.x * d1) * rs);
    o.y = f2bf(((float)h0.y * d0 + (float)h1.y * d1) * rs);
    o.z = f2bf(((float)h0.z * d0 + (float)h1.z * d1) * rs);
    o.w = f2bf(((float)h0.w * d0 + (float)h1.w * d1) * rs);
    *(ushort4*)&ctxq[((size_t)(b * Lq + l)) * Dq + h * DKq + dk4 * 4] = o;
}

// ---------------- output projection: 128x64 tiles, 512 blocks (2/CU) --------
__global__ __launch_bounds__(256) void out_gemm(const u16* __restrict__ A,
                                                const u16* __restrict__ Bw,
                                                float* __restrict__ out) {
    __shared__ __align__(16) union {
        struct { u16 A[128 * 64]; u16 B[64 * 64]; } s;
        float fepi[64 * 68];
    } sm;
    const int m0 = blockIdx.x * 128, n0 = blockIdx.y * 64;
    const int tid = threadIdx.x, w = tid >> 6, lane = tid & 63;
    const int l15 = lane & 15, quad = lane >> 4;
    const int wy = w & 1, wx = (w >> 1) & 1;
    const int r8 = lane >> 3, c8 = lane & 7, csw = c8 ^ r8;
    const int sw = l15 & 7;

    float4v acc[4][2];
    float4v zero = {0.f, 0.f, 0.f, 0.f};
#pragma unroll
    for (int mi = 0; mi < 4; mi++)
#pragma unroll
        for (int ni = 0; ni < 2; ni++) acc[mi][ni] = zero;

    for (int k0 = 0; k0 < 512; k0 += 64) {
#pragma unroll
        for (int i = 0; i < 4; i++) {
            int row = w * 32 + i * 8;
            gload_lds16(&A[(size_t)(m0 + row + r8) * 512 + k0 + csw * 8], &sm.s.A[row * 64]);
        }
#pragma unroll
        for (int i = 0; i < 2; i++) {
            int row = w * 16 + i * 8;
            gload_lds16(&Bw[(size_t)(n0 + row + r8) * 512 + k0 + csw * 8], &sm.s.B[row * 64]);
        }
        __syncthreads();
        short8 af0[4], af1[4], bf0[2], bf1[2];
#pragma unroll
        for (int t = 0; t < 4; t++) {
            int rowA = wy * 64 + t * 16 + l15;
            af0[t] = *(const short8*)&sm.s.A[rowA * 64 + ((quad ^ sw) * 8)];
            af1[t] = *(const short8*)&sm.s.A[rowA * 64 + (((quad + 4) ^ sw) * 8)];
        }
#pragma unroll
        for (int t = 0; t < 2; t++) {
            int rowB = wx * 32 + t * 16 + l15;
            bf0[t] = *(const short8*)&sm.s.B[rowB * 64 + ((quad ^ sw) * 8)];
            bf1[t] = *(const short8*)&sm.s.B[rowB * 64 + (((quad + 4) ^ sw) * 8)];
        }
#pragma unroll
        for (int mi = 0; mi < 4; mi++)
#pragma unroll
            for (int ni = 0; ni < 2; ni++) {
                acc[mi][ni] = mfma16(af0[mi], bf0[ni], acc[mi][ni]);
                acc[mi][ni] = mfma16(af1[mi], bf1[ni], acc[mi][ni]);
            }
        __syncthreads();
    }

    // epilogue: two 64-row passes through LDS -> coalesced b128 fp32 stores
#pragma unroll
    for (int ph = 0; ph < 2; ph++) {
#pragma unroll
        for (int mh = 0; mh < 2; mh++) {
            int mi = ph * 2 + mh;
            int lr = wy * 32 + mh * 16 + quad * 4;
#pragma unroll
            for (int ni = 0; ni < 2; ni++)
#pragma unroll
                for (int r = 0; r < 4; r++)
                    sm.fepi[(lr + r) * 68 + wx * 32 + ni * 16 + l15] = acc[mi][ni][r];
        }
        __syncthreads();
#pragma unroll
        for (int i = 0; i < 4; i++) {
            int flat = i * 1024 + tid * 4;
            int lrow = flat >> 6, col = flat & 63;
            float4 vv = *(const float4*)&sm.fepi[lrow * 68 + col];
            int m = (lrow & 31) + (lrow >> 5) * 64 + ph * 32;
            *(float4*)&out[(size_t)(m0 + m) * 512 + n0 + col] = vv;
        }
        __syncthreads();
    }
}

extern "C" void kernel_launch(void* const* d_in, const int* in_sizes, int n_in,
                              void* d_out, int out_size, void* d_ws, size_t ws_size,
                              hipStream_t stream) {
    const float* x     = (const float*)d_in[0];   // [2,4096,512]
    const float* w_qkv = (const float*)d_in[1];   // [1536,512]
    const float* w_o   = (const float*)d_in[2];   // [512,512]
    float* out = (float*)d_out;

    const size_t N_X   = (size_t)Bq * Lq * Dq;        // 4194304
    const size_t N_WQ  = (size_t)3 * Dq * Dq;         // 786432
    const size_t N_WO  = (size_t)Dq * Dq;             // 262144
    const size_t N_QKV = (size_t)Bq * Hq * Lq * DKq;  // 4194304 each

    u16* xb  = (u16*)d_ws;       // castall in; dead after qkv -> op0
    u16* wqb = xb + N_X;         // dead after qkv -> denp
    u16* wob = wqb + N_WQ;
    u16* qb  = wob + N_WO;       // dead after attn -> final ctx
    u16* kb  = qb + N_QKV;
    u16* vt  = kb + N_QKV;
    u16* o1r = vt + N_QKV;       // op1 region

    _Float16* op0  = (_Float16*)xb;
    _Float16* op1  = (_Float16*)o1r;
    float*    denp = (float*)wqb;
    u16*      ctxq = qb;

    castall<<<dim3(5120), 256, 0, stream>>>(x, w_qkv, w_o, xb, wqb, wob);
    qkv_gemm<<<dim3(64, 12), 256, 0, stream>>>(xb, wqb, qb, kb, vt);
    attn_kern<<<dim3(1024), 256, 0, stream>>>(qb, kb, vt, op0, op1, denp);
    combine<<<dim3(4096), 256, 0, stream>>>(op0, op1, denp, ctxq);
    out_gemm<<<dim3(64, 8), 256, 0, stream>>>(ctxq, wob, out);
}

// Round 11
// 202.953 us; speedup vs baseline: 3.0225x; 3.0225x over previous
//
#include <hip/hip_runtime.h>

// B=2, L=4096, D=512, H=8, DK=64. out = Attn(x W_qkv^T) W_o^T, fp32 io.
// R11: attn/qkv/castall = R8 verbatim (attn 92.8us verified local optimum;
// every restructure R5/R6/R7/R9/R10 regressed -- spill or occupancy).
// combine kernel deleted: split-K combine fused into out_gemm A-staging
// (R7-verified staging) on R10's 512-block 128x64-tile out_gemm shape.

#define Bq 2
#define Lq 4096
#define Dq 512
#define Hq 8
#define DKq 64
#define PST 72  // P row stride (elems): 144B -> 2-way bank aliasing only (free)

using short8  = __attribute__((ext_vector_type(8))) short;
using ushort8 = __attribute__((ext_vector_type(8))) unsigned short;
using float4v = __attribute__((ext_vector_type(4))) float;
typedef unsigned short u16;
typedef unsigned int   u32;

__device__ __forceinline__ u16 f2bf(float f) {
    u32 u = __float_as_uint(f);
    u += 0x7fffu + ((u >> 16) & 1u);   // RNE
    return (u16)(u >> 16);
}

__device__ __forceinline__ float exp2fast(float x) {
#if __has_builtin(__builtin_amdgcn_exp2f)
    return __builtin_amdgcn_exp2f(x);
#else
    return exp2f(x);
#endif
}

__device__ __forceinline__ float4v mfma16(short8 a, short8 b, float4v c) {
    return __builtin_amdgcn_mfma_f32_16x16x32_bf16(a, b, c, 0, 0, 0);
}

__device__ __forceinline__ void gload_lds16(const u16* g, u16* l) {
    __builtin_amdgcn_global_load_lds(
        (const __attribute__((address_space(1))) unsigned int*)g,
        (__attribute__((address_space(3))) unsigned int*)l,
        16, 0, 0);
}

// ---------------- fused cast fp32 -> bf16 ----------------
__global__ __launch_bounds__(256) void castall(const float* __restrict__ x,
                                               const float* __restrict__ wq,
                                               const float* __restrict__ wo,
                                               u16* __restrict__ xb,
                                               u16* __restrict__ wqb,
                                               u16* __restrict__ wob) {
    int g = blockIdx.x;
    const float* s; u16* d; int base;
    if (g < 4096)      { s = x;  d = xb;  base = g * 1024; }
    else if (g < 4864) { s = wq; d = wqb; base = (g - 4096) * 1024; }
    else               { s = wo; d = wob; base = (g - 4864) * 1024; }
    int i = base + threadIdx.x * 4;
    float4 f = *(const float4*)&s[i];
    ushort4 o;
    o.x = f2bf(f.x); o.y = f2bf(f.y); o.z = f2bf(f.z); o.w = f2bf(f.w);
    *(ushort4*)&d[i] = o;
}

// ---------------- QKV proj: 128x128 tile; LDS-bounced coalesced epilogue -----
// q prescaled by 0.125*log2(e) (softmax in exp2 domain); k,v plain.
__global__ __launch_bounds__(256) void qkv_gemm(const u16* __restrict__ A,
                                                const u16* __restrict__ Bw,
                                                u16* __restrict__ qb,
                                                u16* __restrict__ kb,
                                                u16* __restrict__ vt) {
    __shared__ __align__(16) union {
        struct { u16 A[128 * 64]; u16 B[128 * 64]; } s;
        u16 epi[128 * 134];
    } sm;
    const int m0 = blockIdx.x * 128, n0 = blockIdx.y * 128;
    const int tid = threadIdx.x, w = tid >> 6, lane = tid & 63;
    const int l15 = lane & 15, quad = lane >> 4;
    const int wy = w & 1, wx = w >> 1;
    const int r8 = lane >> 3, c8 = lane & 7, csw = c8 ^ r8;
    const int sw = l15 & 7;

    float4v acc[4][4];
    float4v zero = {0.f, 0.f, 0.f, 0.f};
#pragma unroll
    for (int mi = 0; mi < 4; mi++)
#pragma unroll
        for (int ni = 0; ni < 4; ni++) acc[mi][ni] = zero;

    for (int k0 = 0; k0 < 512; k0 += 64) {
#pragma unroll
        for (int i = 0; i < 4; i++) {
            int row = w * 32 + i * 8;
            gload_lds16(&A[(size_t)(m0 + row + r8) * 512 + k0 + csw * 8], &sm.s.A[row * 64]);
            gload_lds16(&Bw[(size_t)(n0 + row + r8) * 512 + k0 + csw * 8], &sm.s.B[row * 64]);
        }
        __syncthreads();
        short8 af0[4], af1[4], bf0[4], bf1[4];
#pragma unroll
        for (int t = 0; t < 4; t++) {
            int rowA = wy * 64 + t * 16 + l15;
            af0[t] = *(const short8*)&sm.s.A[rowA * 64 + ((quad ^ sw) * 8)];
            af1[t] = *(const short8*)&sm.s.A[rowA * 64 + (((quad + 4) ^ sw) * 8)];
            int rowB = wx * 64 + t * 16 + l15;
            bf0[t] = *(const short8*)&sm.s.B[rowB * 64 + ((quad ^ sw) * 8)];
            bf1[t] = *(const short8*)&sm.s.B[rowB * 64 + (((quad + 4) ^ sw) * 8)];
        }
#pragma unroll
        for (int mi = 0; mi < 4; mi++)
#pragma unroll
            for (int ni = 0; ni < 4; ni++) {
                acc[mi][ni] = mfma16(af0[mi], bf0[ni], acc[mi][ni]);
                acc[mi][ni] = mfma16(af1[mi], bf1[ni], acc[mi][ni]);
            }
        __syncthreads();
    }

    const int sel = n0 >> 9;   // block-uniform: 0=q,1=k,2=v
    if (sel < 2) {
        const float sc = (sel == 0) ? 0.18033688f : 1.0f;  // 0.125*log2(e)
#pragma unroll
        for (int mi = 0; mi < 4; mi++)
#pragma unroll
            for (int ni = 0; ni < 4; ni++)
#pragma unroll
                for (int r = 0; r < 4; r++)
                    sm.epi[(wy * 64 + mi * 16 + quad * 4 + r) * 134 + wx * 64 + ni * 16 + l15] =
                        f2bf(acc[mi][ni][r] * sc);
        __syncthreads();
        u16* tgt = (sel == 0) ? qb : kb;
#pragma unroll
        for (int i = 0; i < 8; i++) {
            int flat = i * 2048 + tid * 8;
            int row = flat >> 7, col = flat & 127;
            ushort8 vv = *(const ushort8*)&sm.epi[row * 134 + col];
            int dg = (n0 & 511) + col, h = dg >> 6, dk = dg & 63;
            int mm = m0 + row, b = mm >> 12, l = mm & 4095;
            *(ushort8*)&tgt[((size_t)(b * Hq + h) * Lq + l) * DKq + dk] = vv;
        }
    } else {
#pragma unroll
        for (int mi = 0; mi < 4; mi++)
#pragma unroll
            for (int ni = 0; ni < 4; ni++) {
                ushort4 v4;
                v4.x = f2bf(acc[mi][ni][0]); v4.y = f2bf(acc[mi][ni][1]);
                v4.z = f2bf(acc[mi][ni][2]); v4.w = f2bf(acc[mi][ni][3]);
                *(ushort4*)&sm.epi[(wx * 64 + ni * 16 + l15) * 134 + wy * 64 + mi * 16 + quad * 4] = v4;
            }
        __syncthreads();
#pragma unroll
        for (int i = 0; i < 8; i++) {
            int flat = i * 2048 + tid * 8;
            int vrow = flat >> 7, vcol = flat & 127;
            ushort8 vv = *(const ushort8*)&sm.epi[vrow * 134 + vcol];
            int dg = (n0 & 511) + vrow, h = dg >> 6, dk = dg & 63;
            int mm = m0 + vcol, b = mm >> 12, l = mm & 4095;
            *(ushort8*)&vt[((size_t)(b * Hq + h) * DKq + dk) * Lq + l] = vv;
        }
    }
}

// ---------------- attention: exact R8 structure (92.8us proven) -------------
__global__ __launch_bounds__(256, 4) void attn_kern(const u16* __restrict__ qb,
                                                    const u16* __restrict__ kb,
                                                    const u16* __restrict__ vt,
                                                    _Float16* __restrict__ op0,
                                                    _Float16* __restrict__ op1,
                                                    float* __restrict__ denp) {
    __shared__ __align__(16) u16 Ks[64 * 64];
    __shared__ __align__(16) u16 Vs[64 * 64];
    __shared__ __align__(16) u16 Ps[4 * 32 * PST];
    const int g = blockIdx.x;          // 1024
    const int xcd = g & 7, idx = g >> 3;
    const int bh = xcd * 2 + (idx & 1);
    const int rest = idx >> 1;
    const int split = rest & 1;
    const int q0 = (rest >> 1) * 128;
    const int tid = threadIdx.x;
    const int w = tid >> 6, lane = tid & 63, l15 = lane & 15, quad = lane >> 4;
    const int r8 = lane >> 3, c8 = lane & 7, csw = c8 ^ r8;
    const int sw = l15 & 7;

    const u16* qbase = qb + (size_t)bh * Lq * DKq;
    const u16* kbase = kb + (size_t)bh * Lq * DKq;
    const u16* vbase = vt + (size_t)bh * DKq * Lq;

    short8 aq0[2], aq1[2];
#pragma unroll
    for (int s = 0; s < 2; s++) {
        int qrow = q0 + w * 32 + s * 16 + l15;
        aq0[s] = *(const short8*)&qbase[(size_t)qrow * DKq + quad * 8];
        aq1[s] = *(const short8*)&qbase[(size_t)qrow * DKq + 32 + quad * 8];
    }

    short8 ones8;
#pragma unroll
    for (int j = 0; j < 8; j++) ones8[j] = (short)0x3F80;  // bf16 1.0

    float4v zero = {0.f, 0.f, 0.f, 0.f};
    float4v oacc[2][4], den[2];
#pragma unroll
    for (int s = 0; s < 2; s++) {
        den[s] = zero;
#pragma unroll
        for (int n = 0; n < 4; n++) oacc[s][n] = zero;
    }

    u16* Pw = Ps + w * 32 * PST;
    const int j0base = split * 2048;

    for (int jt = 0; jt < 32; jt++) {
        int j0 = j0base + jt * 64;
        if (w < 2) {
#pragma unroll
            for (int i = 0; i < 4; i++) {
                int base = w * 32 + i * 8;
                gload_lds16(&kbase[(size_t)(j0 + base + r8) * DKq + csw * 8], &Ks[base * 64]);
            }
        } else {
#pragma unroll
            for (int i = 0; i < 4; i++) {
                int base = (w - 2) * 32 + i * 8;
                gload_lds16(&vbase[(size_t)(base + r8) * Lq + j0 + csw * 8], &Vs[base * 64]);
            }
        }
        __syncthreads();

        short8 kf0[4], kf1[4], vf0[4], vf1[4];
#pragma unroll
        for (int n = 0; n < 4; n++) {
            int row = n * 16 + l15;
            kf0[n] = *(const short8*)&Ks[row * 64 + ((quad ^ sw) * 8)];
            kf1[n] = *(const short8*)&Ks[row * 64 + (((quad + 4) ^ sw) * 8)];
            vf0[n] = *(const short8*)&Vs[row * 64 + ((quad ^ sw) * 8)];
            vf1[n] = *(const short8*)&Vs[row * 64 + (((quad + 4) ^ sw) * 8)];
        }

        // S^T = K Q^T -> P = exp2(S) -> LDS (b64 packed writes)
#pragma unroll
        for (int s = 0; s < 2; s++) {
#pragma unroll
            for (int nk = 0; nk < 4; nk++) {
                float4v sv = zero;
                sv = mfma16(kf0[nk], aq0[s], sv);
                sv = mfma16(kf1[nk], aq1[s], sv);
                u32 u0 = __float_as_uint(exp2fast(sv[0])) + 0x8000u;
                u32 u1 = __float_as_uint(exp2fast(sv[1])) + 0x8000u;
                u32 u2 = __float_as_uint(exp2fast(sv[2])) + 0x8000u;
                u32 u3 = __float_as_uint(exp2fast(sv[3])) + 0x8000u;
                uint2 pv;
                pv.x = __builtin_amdgcn_perm(u1, u0, 0x07060302u);
                pv.y = __builtin_amdgcn_perm(u3, u2, 0x07060302u);
                *(uint2*)&Pw[(s * 16 + l15) * PST + nk * 16 + quad * 4] = pv;
            }
        }

        // O += P V ; den += P . 1
#pragma unroll
        for (int s = 0; s < 2; s++) {
            short8 ap0 = *(const short8*)&Pw[(s * 16 + l15) * PST + quad * 8];
            short8 ap1 = *(const short8*)&Pw[(s * 16 + l15) * PST + 32 + quad * 8];
            den[s] = mfma16(ap0, ones8, den[s]);
            den[s] = mfma16(ap1, ones8, den[s]);
#pragma unroll
            for (int n = 0; n < 4; n++) {
                oacc[s][n] = mfma16(ap0, vf0[n], oacc[s][n]);
                oacc[s][n] = mfma16(ap1, vf1[n], oacc[s][n]);
            }
        }
        __syncthreads();
    }

    // epilogue: write normalized partial O (fp16) + partial den (fp32)
    _Float16* op = split ? op1 : op0;
#pragma unroll
    for (int s = 0; s < 2; s++)
#pragma unroll
        for (int r = 0; r < 4; r++) {
            float dv = den[s][r];
            float rd = __builtin_amdgcn_rcpf(dv);
            int row = q0 + w * 32 + s * 16 + quad * 4 + r;
            if (l15 == 0) denp[(size_t)(split * 16 + bh) * Lq + row] = dv;
#pragma unroll
            for (int n = 0; n < 4; n++)
                op[((size_t)bh * Lq + row) * DKq + n * 16 + l15] =
                    (_Float16)(oacc[s][n][r] * rd);
        }
}

// ---------------- output projection with fused split-K combine --------------
// out[8192,512] = combine(op0,op1,denp) @ Wo^T ; head h == k-iter (DK=64).
// 128x64 tiles -> grid (64,8) = 512 blocks (2/CU).
__global__ __launch_bounds__(256) void out_gemm(const _Float16* __restrict__ op0,
                                                const _Float16* __restrict__ op1,
                                                const float* __restrict__ denp,
                                                const u16* __restrict__ Bw,
                                                float* __restrict__ out) {
    __shared__ __align__(16) union {
        struct { u16 A[128 * 64]; u16 B[64 * 64]; } s;
        float fepi[64 * 68];
    } sm;
    const int m0 = blockIdx.x * 128, n0 = blockIdx.y * 64;
    const int tid = threadIdx.x, w = tid >> 6, lane = tid & 63;
    const int l15 = lane & 15, quad = lane >> 4;
    const int wy = w & 1, wx = (w >> 1) & 1;
    const int r8 = lane >> 3, c8 = lane & 7, csw = c8 ^ r8;
    const int sw = l15 & 7;

    float4v acc[4][2];
    float4v zero = {0.f, 0.f, 0.f, 0.f};
#pragma unroll
    for (int mi = 0; mi < 4; mi++)
#pragma unroll
        for (int ni = 0; ni < 2; ni++) acc[mi][ni] = zero;

    for (int k0 = 0; k0 < 512; k0 += 64) {
        const int kk = k0 >> 6;   // head index
        // B: async DMA (bf16 Wo)
#pragma unroll
        for (int i = 0; i < 2; i++) {
            int row = w * 16 + i * 8;
            gload_lds16(&Bw[(size_t)(n0 + row + r8) * 512 + k0 + csw * 8], &sm.s.B[row * 64]);
        }
        // A: manual combined staging from op0/op1/denp (R7-verified path)
#pragma unroll
        for (int i = 0; i < 4; i++) {
            int row = w * 32 + i * 8;
            int mm = m0 + row + r8;
            int b = mm >> 12, l = mm & 4095;
            int bh = b * Hq + kk;
            size_t rowoff = ((size_t)bh * Lq + l) * DKq + csw * 8;
            union { float4 f; _Float16 h[8]; } ua, ub;
            ua.f = *(const float4*)&op0[rowoff];
            ub.f = *(const float4*)&op1[rowoff];
            float d0 = denp[(size_t)bh * Lq + l];
            float d1 = denp[(size_t)(16 + bh) * Lq + l];
            float rs = __builtin_amdgcn_rcpf(d0 + d1);
            ushort8 ov;
#pragma unroll
            for (int j = 0; j < 8; j++)
                ov[j] = f2bf(((float)ua.h[j] * d0 + (float)ub.h[j] * d1) * rs);
            *(ushort8*)&sm.s.A[(row + r8) * 64 + c8 * 8] = ov;
        }
        __syncthreads();
        short8 af0[4], af1[4], bf0[2], bf1[2];
#pragma unroll
        for (int t = 0; t < 4; t++) {
            int rowA = wy * 64 + t * 16 + l15;
            af0[t] = *(const short8*)&sm.s.A[rowA * 64 + ((quad ^ sw) * 8)];
            af1[t] = *(const short8*)&sm.s.A[rowA * 64 + (((quad + 4) ^ sw) * 8)];
        }
#pragma unroll
        for (int t = 0; t < 2; t++) {
            int rowB = wx * 32 + t * 16 + l15;
            bf0[t] = *(const short8*)&sm.s.B[rowB * 64 + ((quad ^ sw) * 8)];
            bf1[t] = *(const short8*)&sm.s.B[rowB * 64 + (((quad + 4) ^ sw) * 8)];
        }
#pragma unroll
        for (int mi = 0; mi < 4; mi++)
#pragma unroll
            for (int ni = 0; ni < 2; ni++) {
                acc[mi][ni] = mfma16(af0[mi], bf0[ni], acc[mi][ni]);
                acc[mi][ni] = mfma16(af1[mi], bf1[ni], acc[mi][ni]);
            }
        __syncthreads();
    }

    // epilogue: two 64-row passes through LDS -> coalesced b128 fp32 stores
#pragma unroll
    for (int ph = 0; ph < 2; ph++) {
#pragma unroll
        for (int mh = 0; mh < 2; mh++) {
            int mi = ph * 2 + mh;
            int lr = wy * 32 + mh * 16 + quad * 4;
#pragma unroll
            for (int ni = 0; ni < 2; ni++)
#pragma unroll
                for (int r = 0; r < 4; r++)
                    sm.fepi[(lr + r) * 68 + wx * 32 + ni * 16 + l15] = acc[mi][ni][r];
        }
        __syncthreads();
#pragma unroll
        for (int i = 0; i < 4; i++) {
            int flat = i * 1024 + tid * 4;
            int lrow = flat >> 6, col = flat & 63;
            float4 vv = *(const float4*)&sm.fepi[lrow * 68 + col];
            int m = (lrow & 31) + (lrow >> 5) * 64 + ph * 32;
            *(float4*)&out[(size_t)(m0 + m) * 512 + n0 + col] = vv;
        }
        __syncthreads();
    }
}

extern "C" void kernel_launch(void* const* d_in, const int* in_sizes, int n_in,
                              void* d_out, int out_size, void* d_ws, size_t ws_size,
                              hipStream_t stream) {
    const float* x     = (const float*)d_in[0];   // [2,4096,512]
    const float* w_qkv = (const float*)d_in[1];   // [1536,512]
    const float* w_o   = (const float*)d_in[2];   // [512,512]
    float* out = (float*)d_out;

    const size_t N_X   = (size_t)Bq * Lq * Dq;        // 4194304
    const size_t N_WQ  = (size_t)3 * Dq * Dq;         // 786432
    const size_t N_WO  = (size_t)Dq * Dq;             // 262144
    const size_t N_QKV = (size_t)Bq * Hq * Lq * DKq;  // 4194304 each

    u16* xb  = (u16*)d_ws;       // castall in; dead after qkv -> op0
    u16* wqb = xb + N_X;         // dead after qkv -> denp
    u16* wob = wqb + N_WQ;
    u16* qb  = wob + N_WO;
    u16* kb  = qb + N_QKV;
    u16* vt  = kb + N_QKV;
    u16* o1r = vt + N_QKV;       // op1 region

    _Float16* op0  = (_Float16*)xb;
    _Float16* op1  = (_Float16*)o1r;
    float*    denp = (float*)wqb;

    castall<<<dim3(5120), 256, 0, stream>>>(x, w_qkv, w_o, xb, wqb, wob);
    qkv_gemm<<<dim3(64, 12), 256, 0, stream>>>(xb, wqb, qb, kb, vt);
    attn_kern<<<dim3(1024), 256, 0, stream>>>(qb, kb, vt, op0, op1, denp);
    out_gemm<<<dim3(64, 8), 256, 0, stream>>>(op0, op1, denp, wob, out);
}

// Round 12
// 197.287 us; speedup vs baseline: 3.1093x; 1.0287x over previous
//
#include <hip/hip_runtime.h>

// B=2, L=4096, D=512, H=8, DK=64. out = Attn(x W_qkv^T) W_o^T, fp32 io.
// R12: R8 everywhere (verified optimum), plus: split-K generalized to S=3
// (grid 1536 = 6 blocks/CU = two clean 3-resident rounds; kills the 1024-block
// straggler tail). S=3 needs 50 MB ws -> guarded on ws_size, falls back to
// exact R8 S=2. out_gemm reverted to R8 (R11's fused combine redid work 8x).

#define Bq 2
#define Lq 4096
#define Dq 512
#define Hq 8
#define DKq 64
#define PST 72  // P row stride (elems): 144B -> 2-way bank aliasing only (free)

using short8  = __attribute__((ext_vector_type(8))) short;
using ushort8 = __attribute__((ext_vector_type(8))) unsigned short;
using float4v = __attribute__((ext_vector_type(4))) float;
using half4   = __attribute__((ext_vector_type(4))) _Float16;
typedef unsigned short u16;
typedef unsigned int   u32;

__device__ __forceinline__ u16 f2bf(float f) {
    u32 u = __float_as_uint(f);
    u += 0x7fffu + ((u >> 16) & 1u);   // RNE
    return (u16)(u >> 16);
}

__device__ __forceinline__ float exp2fast(float x) {
#if __has_builtin(__builtin_amdgcn_exp2f)
    return __builtin_amdgcn_exp2f(x);
#else
    return exp2f(x);
#endif
}

__device__ __forceinline__ float4v mfma16(short8 a, short8 b, float4v c) {
    return __builtin_amdgcn_mfma_f32_16x16x32_bf16(a, b, c, 0, 0, 0);
}

__device__ __forceinline__ void gload_lds16(const u16* g, u16* l) {
    __builtin_amdgcn_global_load_lds(
        (const __attribute__((address_space(1))) unsigned int*)g,
        (__attribute__((address_space(3))) unsigned int*)l,
        16, 0, 0);
}

// ---------------- fused cast fp32 -> bf16 ----------------
__global__ __launch_bounds__(256) void castall(const float* __restrict__ x,
                                               const float* __restrict__ wq,
                                               const float* __restrict__ wo,
                                               u16* __restrict__ xb,
                                               u16* __restrict__ wqb,
                                               u16* __restrict__ wob) {
    int g = blockIdx.x;
    const float* s; u16* d; int base;
    if (g < 4096)      { s = x;  d = xb;  base = g * 1024; }
    else if (g < 4864) { s = wq; d = wqb; base = (g - 4096) * 1024; }
    else               { s = wo; d = wob; base = (g - 4864) * 1024; }
    int i = base + threadIdx.x * 4;
    float4 f = *(const float4*)&s[i];
    ushort4 o;
    o.x = f2bf(f.x); o.y = f2bf(f.y); o.z = f2bf(f.z); o.w = f2bf(f.w);
    *(ushort4*)&d[i] = o;
}

// ---------------- QKV proj: 128x128 tile; LDS-bounced coalesced epilogue -----
// q prescaled by 0.125*log2(e) (softmax in exp2 domain); k,v plain.
__global__ __launch_bounds__(256) void qkv_gemm(const u16* __restrict__ A,
                                                const u16* __restrict__ Bw,
                                                u16* __restrict__ qb,
                                                u16* __restrict__ kb,
                                                u16* __restrict__ vt) {
    __shared__ __align__(16) union {
        struct { u16 A[128 * 64]; u16 B[128 * 64]; } s;
        u16 epi[128 * 134];
    } sm;
    const int m0 = blockIdx.x * 128, n0 = blockIdx.y * 128;
    const int tid = threadIdx.x, w = tid >> 6, lane = tid & 63;
    const int l15 = lane & 15, quad = lane >> 4;
    const int wy = w & 1, wx = w >> 1;
    const int r8 = lane >> 3, c8 = lane & 7, csw = c8 ^ r8;
    const int sw = l15 & 7;

    float4v acc[4][4];
    float4v zero = {0.f, 0.f, 0.f, 0.f};
#pragma unroll
    for (int mi = 0; mi < 4; mi++)
#pragma unroll
        for (int ni = 0; ni < 4; ni++) acc[mi][ni] = zero;

    for (int k0 = 0; k0 < 512; k0 += 64) {
#pragma unroll
        for (int i = 0; i < 4; i++) {
            int row = w * 32 + i * 8;
            gload_lds16(&A[(size_t)(m0 + row + r8) * 512 + k0 + csw * 8], &sm.s.A[row * 64]);
            gload_lds16(&Bw[(size_t)(n0 + row + r8) * 512 + k0 + csw * 8], &sm.s.B[row * 64]);
        }
        __syncthreads();
        short8 af0[4], af1[4], bf0[4], bf1[4];
#pragma unroll
        for (int t = 0; t < 4; t++) {
            int rowA = wy * 64 + t * 16 + l15;
            af0[t] = *(const short8*)&sm.s.A[rowA * 64 + ((quad ^ sw) * 8)];
            af1[t] = *(const short8*)&sm.s.A[rowA * 64 + (((quad + 4) ^ sw) * 8)];
            int rowB = wx * 64 + t * 16 + l15;
            bf0[t] = *(const short8*)&sm.s.B[rowB * 64 + ((quad ^ sw) * 8)];
            bf1[t] = *(const short8*)&sm.s.B[rowB * 64 + (((quad + 4) ^ sw) * 8)];
        }
#pragma unroll
        for (int mi = 0; mi < 4; mi++)
#pragma unroll
            for (int ni = 0; ni < 4; ni++) {
                acc[mi][ni] = mfma16(af0[mi], bf0[ni], acc[mi][ni]);
                acc[mi][ni] = mfma16(af1[mi], bf1[ni], acc[mi][ni]);
            }
        __syncthreads();
    }

    const int sel = n0 >> 9;   // block-uniform: 0=q,1=k,2=v
    if (sel < 2) {
        const float sc = (sel == 0) ? 0.18033688f : 1.0f;  // 0.125*log2(e)
#pragma unroll
        for (int mi = 0; mi < 4; mi++)
#pragma unroll
            for (int ni = 0; ni < 4; ni++)
#pragma unroll
                for (int r = 0; r < 4; r++)
                    sm.epi[(wy * 64 + mi * 16 + quad * 4 + r) * 134 + wx * 64 + ni * 16 + l15] =
                        f2bf(acc[mi][ni][r] * sc);
        __syncthreads();
        u16* tgt = (sel == 0) ? qb : kb;
#pragma unroll
        for (int i = 0; i < 8; i++) {
            int flat = i * 2048 + tid * 8;
            int row = flat >> 7, col = flat & 127;
            ushort8 vv = *(const ushort8*)&sm.epi[row * 134 + col];
            int dg = (n0 & 511) + col, h = dg >> 6, dk = dg & 63;
            int mm = m0 + row, b = mm >> 12, l = mm & 4095;
            *(ushort8*)&tgt[((size_t)(b * Hq + h) * Lq + l) * DKq + dk] = vv;
        }
    } else {
#pragma unroll
        for (int mi = 0; mi < 4; mi++)
#pragma unroll
            for (int ni = 0; ni < 4; ni++) {
                ushort4 v4;
                v4.x = f2bf(acc[mi][ni][0]); v4.y = f2bf(acc[mi][ni][1]);
                v4.z = f2bf(acc[mi][ni][2]); v4.w = f2bf(acc[mi][ni][3]);
                *(ushort4*)&sm.epi[(wx * 64 + ni * 16 + l15) * 134 + wy * 64 + mi * 16 + quad * 4] = v4;
            }
        __syncthreads();
#pragma unroll
        for (int i = 0; i < 8; i++) {
            int flat = i * 2048 + tid * 8;
            int vrow = flat >> 7, vcol = flat & 127;
            ushort8 vv = *(const ushort8*)&sm.epi[vrow * 134 + vcol];
            int dg = (n0 & 511) + vrow, h = dg >> 6, dk = dg & 63;
            int mm = m0 + vcol, b = mm >> 12, l = mm & 4095;
            *(ushort8*)&vt[((size_t)(b * Hq + h) * DKq + dk) * Lq + l] = vv;
        }
    }
}

// ---------------- attention: R8 structure, generalized split-K (S=2 or 3) ---
__global__ __launch_bounds__(256, 4) void attn_kern(const u16* __restrict__ qb,
                                                    const u16* __restrict__ kb,
                                                    const u16* __restrict__ vt,
                                                    _Float16* __restrict__ op0,
                                                    _Float16* __restrict__ op1,
                                                    _Float16* __restrict__ op2,
                                                    float* __restrict__ denp,
                                                    int S) {
    __shared__ __align__(16) u16 Ks[64 * 64];
    __shared__ __align__(16) u16 Vs[64 * 64];
    __shared__ __align__(16) u16 Ps[4 * 32 * PST];
    const int g = blockIdx.x;
    const int xcd = g & 7, idx = g >> 3;
    const int bh = xcd * 2 + (idx & 1);
    const int rest = idx >> 1;           // [0, 32*S)
    const int split = rest % 3 == rest - (rest / 3) * 3 ? (S == 3 ? rest % 3 : (rest & 1)) : 0;
    const int q0 = (S == 3 ? rest / 3 : rest >> 1) * 128;
    int kstart, kiters;
    if (S == 2) { kstart = split * 2048; kiters = 32; }
    else        { kstart = (split == 0) ? 0 : 1408 + (split - 1) * 1344;
                  kiters = (split == 0) ? 22 : 21; }
    const int tid = threadIdx.x;
    const int w = tid >> 6, lane = tid & 63, l15 = lane & 15, quad = lane >> 4;
    const int r8 = lane >> 3, c8 = lane & 7, csw = c8 ^ r8;
    const int sw = l15 & 7;

    const u16* qbase = qb + (size_t)bh * Lq * DKq;
    const u16* kbase = kb + (size_t)bh * Lq * DKq;
    const u16* vbase = vt + (size_t)bh * DKq * Lq;

    short8 aq0[2], aq1[2];
#pragma unroll
    for (int s = 0; s < 2; s++) {
        int qrow = q0 + w * 32 + s * 16 + l15;
        aq0[s] = *(const short8*)&qbase[(size_t)qrow * DKq + quad * 8];
        aq1[s] = *(const short8*)&qbase[(size_t)qrow * DKq + 32 + quad * 8];
    }

    short8 ones8;
#pragma unroll
    for (int j = 0; j < 8; j++) ones8[j] = (short)0x3F80;  // bf16 1.0

    float4v zero = {0.f, 0.f, 0.f, 0.f};
    float4v oacc[2][4], den[2];
#pragma unroll
    for (int s = 0; s < 2; s++) {
        den[s] = zero;
#pragma unroll
        for (int n = 0; n < 4; n++) oacc[s][n] = zero;
    }

    u16* Pw = Ps + w * 32 * PST;

    for (int jt = 0; jt < kiters; jt++) {
        int j0 = kstart + jt * 64;
        if (w < 2) {
#pragma unroll
            for (int i = 0; i < 4; i++) {
                int base = w * 32 + i * 8;
                gload_lds16(&kbase[(size_t)(j0 + base + r8) * DKq + csw * 8], &Ks[base * 64]);
            }
        } else {
#pragma unroll
            for (int i = 0; i < 4; i++) {
                int base = (w - 2) * 32 + i * 8;
                gload_lds16(&vbase[(size_t)(base + r8) * Lq + j0 + csw * 8], &Vs[base * 64]);
            }
        }
        __syncthreads();

        short8 kf0[4], kf1[4], vf0[4], vf1[4];
#pragma unroll
        for (int n = 0; n < 4; n++) {
            int row = n * 16 + l15;
            kf0[n] = *(const short8*)&Ks[row * 64 + ((quad ^ sw) * 8)];
            kf1[n] = *(const short8*)&Ks[row * 64 + (((quad + 4) ^ sw) * 8)];
            vf0[n] = *(const short8*)&Vs[row * 64 + ((quad ^ sw) * 8)];
            vf1[n] = *(const short8*)&Vs[row * 64 + (((quad + 4) ^ sw) * 8)];
        }

        // S^T = K Q^T -> P = exp2(S) -> LDS (b64 packed writes)
#pragma unroll
        for (int s = 0; s < 2; s++) {
#pragma unroll
            for (int nk = 0; nk < 4; nk++) {
                float4v sv = zero;
                sv = mfma16(kf0[nk], aq0[s], sv);
                sv = mfma16(kf1[nk], aq1[s], sv);
                u32 u0 = __float_as_uint(exp2fast(sv[0])) + 0x8000u;
                u32 u1 = __float_as_uint(exp2fast(sv[1])) + 0x8000u;
                u32 u2 = __float_as_uint(exp2fast(sv[2])) + 0x8000u;
                u32 u3 = __float_as_uint(exp2fast(sv[3])) + 0x8000u;
                uint2 pv;
                pv.x = __builtin_amdgcn_perm(u1, u0, 0x07060302u);
                pv.y = __builtin_amdgcn_perm(u3, u2, 0x07060302u);
                *(uint2*)&Pw[(s * 16 + l15) * PST + nk * 16 + quad * 4] = pv;
            }
        }

        // O += P V ; den += P . 1
#pragma unroll
        for (int s = 0; s < 2; s++) {
            short8 ap0 = *(const short8*)&Pw[(s * 16 + l15) * PST + quad * 8];
            short8 ap1 = *(const short8*)&Pw[(s * 16 + l15) * PST + 32 + quad * 8];
            den[s] = mfma16(ap0, ones8, den[s]);
            den[s] = mfma16(ap1, ones8, den[s]);
#pragma unroll
            for (int n = 0; n < 4; n++) {
                oacc[s][n] = mfma16(ap0, vf0[n], oacc[s][n]);
                oacc[s][n] = mfma16(ap1, vf1[n], oacc[s][n]);
            }
        }
        __syncthreads();
    }

    // epilogue: write normalized partial O (fp16) + partial den (fp32)
    _Float16* op = (split == 0) ? op0 : ((split == 1) ? op1 : op2);
#pragma unroll
    for (int s = 0; s < 2; s++)
#pragma unroll
        for (int r = 0; r < 4; r++) {
            float dv = den[s][r];
            float rd = __builtin_amdgcn_rcpf(dv);
            int row = q0 + w * 32 + s * 16 + quad * 4 + r;
            if (l15 == 0) denp[(size_t)(split * 16 + bh) * Lq + row] = dv;
#pragma unroll
            for (int n = 0; n < 4; n++)
                op[((size_t)bh * Lq + row) * DKq + n * 16 + l15] =
                    (_Float16)(oacc[s][n][r] * rd);
        }
}

// ---------------- combine: ctx = sum(o_s * d_s) / sum(d_s), bf16 ------------
__global__ __launch_bounds__(256) void combine(const _Float16* __restrict__ op0,
                                               const _Float16* __restrict__ op1,
                                               const _Float16* __restrict__ op2,
                                               const float* __restrict__ denp,
                                               u16* __restrict__ ctxq, int S) {
    int t = blockIdx.x * 256 + threadIdx.x;  // 1,048,576
    int dk4 = t & 15, l = (t >> 4) & 4095, bh = t >> 16;
    size_t r0 = (size_t)bh * Lq + l;
    half4 h0 = *(const half4*)&op0[r0 * DKq + dk4 * 4];
    half4 h1 = *(const half4*)&op1[r0 * DKq + dk4 * 4];
    float d0 = denp[r0];
    float d1 = denp[(size_t)(16 + bh) * Lq + l];
    float a0 = (float)h0.x * d0 + (float)h1.x * d1;
    float a1 = (float)h0.y * d0 + (float)h1.y * d1;
    float a2 = (float)h0.z * d0 + (float)h1.z * d1;
    float a3 = (float)h0.w * d0 + (float)h1.w * d1;
    float dt = d0 + d1;
    if (S == 3) {
        half4 h2 = *(const half4*)&op2[r0 * DKq + dk4 * 4];
        float d2 = denp[(size_t)(32 + bh) * Lq + l];
        a0 += (float)h2.x * d2; a1 += (float)h2.y * d2;
        a2 += (float)h2.z * d2; a3 += (float)h2.w * d2;
        dt += d2;
    }
    float rs = __builtin_amdgcn_rcpf(dt);
    int b = bh >> 3, h = bh & 7;
    ushort4 o;
    o.x = f2bf(a0 * rs); o.y = f2bf(a1 * rs);
    o.z = f2bf(a2 * rs); o.w = f2bf(a3 * rs);
    *(ushort4*)&ctxq[((size_t)(b * Lq + l)) * Dq + h * DKq + dk4 * 4] = o;
}

// ---------------- output projection: fp32 out, LDS-bounced epilogue (R8) ----
__global__ __launch_bounds__(256) void out_gemm(const u16* __restrict__ A,
                                                const u16* __restrict__ Bw,
                                                float* __restrict__ out) {
    __shared__ __align__(16) union {
        struct { u16 A[128 * 64]; u16 B[128 * 64]; } s;
        float fepi[64 * 132];
    } sm;
    const int m0 = blockIdx.x * 128, n0 = blockIdx.y * 128;
    const int tid = threadIdx.x, w = tid >> 6, lane = tid & 63;
    const int l15 = lane & 15, quad = lane >> 4;
    const int wy = w & 1, wx = w >> 1;
    const int r8 = lane >> 3, c8 = lane & 7, csw = c8 ^ r8;
    const int sw = l15 & 7;

    float4v acc[4][4];
    float4v zero = {0.f, 0.f, 0.f, 0.f};
#pragma unroll
    for (int mi = 0; mi < 4; mi++)
#pragma unroll
        for (int ni = 0; ni < 4; ni++) acc[mi][ni] = zero;

    for (int k0 = 0; k0 < 512; k0 += 64) {
#pragma unroll
        for (int i = 0; i < 4; i++) {
            int row = w * 32 + i * 8;
            gload_lds16(&A[(size_t)(m0 + row + r8) * 512 + k0 + csw * 8], &sm.s.A[row * 64]);
            gload_lds16(&Bw[(size_t)(n0 + row + r8) * 512 + k0 + csw * 8], &sm.s.B[row * 64]);
        }
        __syncthreads();
        short8 af0[4], af1[4], bf0[4], bf1[4];
#pragma unroll
        for (int t = 0; t < 4; t++) {
            int rowA = wy * 64 + t * 16 + l15;
            af0[t] = *(const short8*)&sm.s.A[rowA * 64 + ((quad ^ sw) * 8)];
            af1[t] = *(const short8*)&sm.s.A[rowA * 64 + (((quad + 4) ^ sw) * 8)];
            int rowB = wx * 64 + t * 16 + l15;
            bf0[t] = *(const short8*)&sm.s.B[rowB * 64 + ((quad ^ sw) * 8)];
            bf1[t] = *(const short8*)&sm.s.B[rowB * 64 + (((quad + 4) ^ sw) * 8)];
        }
#pragma unroll
        for (int mi = 0; mi < 4; mi++)
#pragma unroll
            for (int ni = 0; ni < 4; ni++) {
                acc[mi][ni] = mfma16(af0[mi], bf0[ni], acc[mi][ni]);
                acc[mi][ni] = mfma16(af1[mi], bf1[ni], acc[mi][ni]);
            }
        __syncthreads();
    }

#pragma unroll
    for (int ph = 0; ph < 2; ph++) {
#pragma unroll
        for (int mh = 0; mh < 2; mh++) {
            int mi = ph * 2 + mh;
            int lr = wy * 32 + mh * 16 + quad * 4;
#pragma unroll
            for (int ni = 0; ni < 4; ni++)
#pragma unroll
                for (int r = 0; r < 4; r++)
                    sm.fepi[(lr + r) * 132 + wx * 64 + ni * 16 + l15] = acc[mi][ni][r];
        }
        __syncthreads();
#pragma unroll
        for (int i = 0; i < 8; i++) {
            int flat = i * 1024 + tid * 4;
            int lrow = flat >> 7, col = flat & 127;
            float4 vv = *(const float4*)&sm.fepi[lrow * 132 + col];
            int m = (lrow & 31) + (lrow >> 5) * 64 + ph * 32;
            *(float4*)&out[(size_t)(m0 + m) * 512 + n0 + col] = vv;
        }
        __syncthreads();
    }
}

extern "C" void kernel_launch(void* const* d_in, const int* in_sizes, int n_in,
                              void* d_out, int out_size, void* d_ws, size_t ws_size,
                              hipStream_t stream) {
    const float* x     = (const float*)d_in[0];   // [2,4096,512]
    const float* w_qkv = (const float*)d_in[1];   // [1536,512]
    const float* w_o   = (const float*)d_in[2];   // [512,512]
    float* out = (float*)d_out;

    const size_t N_X   = (size_t)Bq * Lq * Dq;        // 4194304
    const size_t N_WQ  = (size_t)3 * Dq * Dq;         // 786432
    const size_t N_WO  = (size_t)Dq * Dq;             // 262144
    const size_t N_QKV = (size_t)Bq * Hq * Lq * DKq;  // 4194304 each

    u16* xb  = (u16*)d_ws;       // castall in; dead after qkv -> op0
    u16* wqb = xb + N_X;         // dead after qkv -> denp (needs <= 768 KB)
    u16* wob = wqb + N_WQ;
    u16* qb  = wob + N_WO;       // dead after attn -> final ctx
    u16* kb  = qb + N_QKV;
    u16* vt  = kb + N_QKV;
    u16* o1r = vt + N_QKV;       // op1 region; op2 = o1r + N_QKV (S=3 only)

    // S=3 needs bytes up to o1r + 2*N_QKV elems = 50 MB exactly.
    const size_t need3 = (size_t)(o1r + 2 * N_QKV - (u16*)d_ws) * sizeof(u16);
    const int S = (ws_size >= need3) ? 3 : 2;

    _Float16* op0  = (_Float16*)xb;
    _Float16* op1  = (_Float16*)o1r;
    _Float16* op2  = (_Float16*)(o1r + N_QKV);  // only touched when S==3
    float*    denp = (float*)wqb;
    u16*      ctxq = qb;

    castall<<<dim3(5120), 256, 0, stream>>>(x, w_qkv, w_o, xb, wqb, wob);
    qkv_gemm<<<dim3(64, 12), 256, 0, stream>>>(xb, wqb, qb, kb, vt);
    attn_kern<<<dim3(512 * S), 256, 0, stream>>>(qb, kb, vt, op0, op1, op2, denp, S);
    combine<<<dim3(4096), 256, 0, stream>>>(op0, op1, op2, denp, ctxq, S);
    out_gemm<<<dim3(64, 4), 256, 0, stream>>>(ctxq, wob, out);
}